// Round 5
// baseline (227.542 us; speedup 1.0000x reference)
//
#include <hip/hip_runtime.h>
#include <hip/hip_fp16.h>

#define Bc 4
#define Sc 2048
#define Dc 768
#define Hc 12
#define DKc 64

typedef _Float16 f16;
typedef __attribute__((ext_vector_type(8))) _Float16 f16x8;
typedef __attribute__((ext_vector_type(4))) _Float16 f16x4;
typedef __attribute__((ext_vector_type(4))) float f32x4;

static __device__ __forceinline__ f32x4 mfma16(f16x8 a, f16x8 b, f32x4 c) {
  return __builtin_amdgcn_mfma_f32_16x16x32_f16(a, b, c, 0, 0, 0);
}

// async global->LDS, 16B per lane. LDS dest is wave-uniform base + lane*16.
#define GLD16(g, l)                                              \
  __builtin_amdgcn_global_load_lds(                              \
      (const __attribute__((address_space(1))) void*)(g),        \
      (__attribute__((address_space(3))) void*)(l), 16, 0, 0)

// T2 XOR swizzle: row stride 128B, byte col ^ ((row&7)<<4).  colB in [0,128).
#define SWZ(row, colB) (((row) << 7) + ((colB) ^ (((row) & 7) << 4)))

// ---------------- fused f32 -> f16 conversion (5 segments) ----------------
__global__ __launch_bounds__(256) void cvt5(
    const float* __restrict__ z, const float* __restrict__ w0,
    const float* __restrict__ w1, const float* __restrict__ w2,
    const float* __restrict__ w3, f16* __restrict__ oz, f16* __restrict__ o0,
    f16* __restrict__ o1, f16* __restrict__ o2, f16* __restrict__ o3) {
  const int bid = blockIdx.x;
  const float* in;
  f16* out;
  int i0;
  if (bid < 6144)      { in = z;  out = oz; i0 = bid * 256; }
  else if (bid < 6720) { in = w0; out = o0; i0 = (bid - 6144) * 256; }
  else if (bid < 7296) { in = w1; out = o1; i0 = (bid - 6720) * 256; }
  else if (bid < 7872) { in = w2; out = o2; i0 = (bid - 7296) * 256; }
  else                 { in = w3; out = o3; i0 = (bid - 7872) * 256; }
  const int i = i0 + threadIdx.x;
  float4 v = reinterpret_cast<const float4*>(in)[i];
  f16x4 o;
  o[0] = (f16)v.x; o[1] = (f16)v.y; o[2] = (f16)v.z; o[3] = (f16)v.w;
  reinterpret_cast<f16x4*>(out)[i] = o;
}

// ------------- 128x128 MFMA GEMM body, 4 waves (m97 structure) --------------
#define GEMM_CORE(Ab, Bb, K)                                                   \
  __shared__ f16 As[128][32];                                                  \
  __shared__ f16 Bs[128][32];                                                  \
  f32x4 acc[4][4] = {};                                                        \
  const int srow = lane >> 2;                                                  \
  const int scol = (lane & 3) * 8;                                             \
  const f16* Ag = (Ab) + (long)(w * 32 + srow) * (K) + scol;                   \
  const f16* Bg = (Bb) + (long)(w * 32 + srow) * (K) + scol;                   \
  f16* As0 = &As[w * 32][0];                                                   \
  f16* As1 = &As[w * 32 + 16][0];                                              \
  f16* Bs0 = &Bs[w * 32][0];                                                   \
  f16* Bs1 = &Bs[w * 32 + 16][0];                                              \
  const long k16 = (long)16 * (K);                                             \
  for (int k0 = 0; k0 < (K); k0 += 32) {                                       \
    GLD16(Ag + k0, As0);                                                       \
    GLD16(Ag + k0 + k16, As1);                                                 \
    GLD16(Bg + k0, Bs0);                                                       \
    GLD16(Bg + k0 + k16, Bs1);                                                 \
    __syncthreads();                                                           \
    f16x8 af[4], bf[4];                                                        \
    _Pragma("unroll") for (int i = 0; i < 4; ++i) {                            \
      af[i] = *reinterpret_cast<const f16x8*>(&As[wr * 64 + i * 16 + l15][lg * 8]); \
      bf[i] = *reinterpret_cast<const f16x8*>(&Bs[wc * 64 + i * 16 + l15][lg * 8]); \
    }                                                                          \
    _Pragma("unroll") for (int mi = 0; mi < 4; ++mi)                           \
      _Pragma("unroll") for (int ni = 0; ni < 4; ++ni)                         \
        acc[mi][ni] = mfma16(af[mi], bf[ni], acc[mi][ni]);                     \
    __syncthreads();                                                           \
  }

// Fused QKV projection: grid (M/128, 18). blockIdx.y: 0-5 Q, 6-11 K, 12-17 V.
__global__ __launch_bounds__(256) void gemm_qkv(
    const f16* __restrict__ zb, const f16* __restrict__ wq,
    const f16* __restrict__ wk, const f16* __restrict__ wv,
    const float* __restrict__ bq, const float* __restrict__ bk,
    const float* __restrict__ bv, f16* __restrict__ Qb, f16* __restrict__ Kb,
    f16* __restrict__ Vt) {
  const int tid = threadIdx.x;
  const int lane = tid & 63;
  const int w = tid >> 6;
  const int wr = w >> 1, wc = w & 1;
  const int l15 = lane & 15, lg = lane >> 4;
  const int sel = blockIdx.y / 6;
  const long m0 = (long)blockIdx.x * 128;
  const long n0 = (long)(blockIdx.y % 6) * 128;
  const f16* Bw = sel == 0 ? wq : sel == 1 ? wk : wv;
  const float* bias = sel == 0 ? bq : sel == 1 ? bk : bv;
  const f16* Ab = zb + m0 * Dc;
  const f16* Bb = Bw + n0 * Dc;

  GEMM_CORE(Ab, Bb, Dc)

  f16* dq = sel == 0 ? Qb : Kb;
#pragma unroll
  for (int mi = 0; mi < 4; ++mi) {
#pragma unroll
    for (int ni = 0; ni < 4; ++ni) {
      const long col = n0 + wc * 64 + ni * 16 + l15;
      const float bv2 = bias[col];
#pragma unroll
      for (int j = 0; j < 4; ++j) {
        const long row = m0 + wr * 64 + mi * 16 + lg * 4 + j;
        const float val = acc[mi][ni][j] + bv2;
        if (sel < 2) {
          dq[row * Dc + col] = (f16)val;
        } else {
          const long b = row >> 11, s = row & 2047;
          Vt[(b * Dc + col) * (long)Sc + s] = (f16)val;
        }
      }
    }
  }
}

// fc: dst f32 row-major [M][N], + bias.
__global__ __launch_bounds__(256) void gemm_fc(
    const f16* __restrict__ A, const f16* __restrict__ Bw,
    const float* __restrict__ bias, float* __restrict__ dst, int N, int K) {
  const int tid = threadIdx.x;
  const int lane = tid & 63;
  const int w = tid >> 6;
  const int wr = w >> 1, wc = w & 1;
  const int l15 = lane & 15, lg = lane >> 4;
  const long m0 = (long)blockIdx.x * 128;
  const long n0 = (long)blockIdx.y * 128;
  const f16* Ab = A + m0 * K;
  const f16* Bb = Bw + n0 * K;

  GEMM_CORE(Ab, Bb, K)

#pragma unroll
  for (int mi = 0; mi < 4; ++mi) {
#pragma unroll
    for (int ni = 0; ni < 4; ++ni) {
      const long col = n0 + wc * 64 + ni * 16 + l15;
      const float bv = bias[col];
#pragma unroll
      for (int j = 0; j < 4; ++j) {
        const long row = m0 + wr * 64 + mi * 16 + lg * 4 + j;
        dst[row * N + col] = acc[mi][ni][j] + bv;
      }
    }
  }
}

// ---------------- fused attention + avg_weights mega-kernel -----------------
// 1792 blocks, 512 threads. Role by slot%7: 3 attn : 4 avg, XCD-aware both.
// attn: 8 waves, 128 q-rows, KVBLK=64, swapped QK^T, T2/T5/T13/T14 as before.
// avg:  8-wave 128x128 GEMM (wave=64x32), out = Q @ K^T / 96, f32.
__global__ __launch_bounds__(512, 4) void fused_aw(
    const f16* __restrict__ Q, const f16* __restrict__ Km,
    const f16* __restrict__ Vt, f16* __restrict__ ctx,
    float* __restrict__ avg) {
  __shared__ f16 smem[16384];  // 32 KB
  const int tid = threadIdx.x;
  const int lane = tid & 63;
  const int w = tid >> 6;              // 0..7
  const int l15 = lane & 15, lg = lane >> 4;
  const int bid = blockIdx.x;
  const int xcd = bid & 7, slot = bid >> 3;
  const int g = slot / 7, r = slot - g * 7;

  if (r < 3) {
    // ======================= attention role =======================
    const int lid = xcd * 96 + g * 3 + r;  // [0,768): 6 (b,h) panels per XCD
    const int qt = lid & 15;
    const int h  = (lid >> 4) % Hc;
    const int b  = lid / (16 * Hc);
    const int q0 = qt * 128 + w * 16;

    char* kb = (char*)smem;              //  8 KB
    char* vb = (char*)smem + 8192;       //  8 KB
    char* pb = (char*)smem + 16384 + (w << 11);  // 16 KB, per-wave 2KB

    f16x8 qf[2];
    {
      const f16* qp = Q + ((long)(b * Sc + q0 + l15)) * Dc + h * DKc + lg * 8;
      qf[0] = *reinterpret_cast<const f16x8*>(qp);
      qf[1] = *reinterpret_cast<const f16x8*>(qp + 32);
    }

    const int srow = tid >> 3;           // 0..63
    const int scolB = (tid & 7) * 16;    // byte col 0..112
    const f16* Kg = Km + (long)(b * Sc) * Dc + h * DKc;
    const f16* Vg = Vt + ((long)(b * Dc + h * DKc)) * Sc;

    const float c2 = 0.18033688011f;     // log2(e) / temp, temp = 8
    float m2 = -1e30f, l_run = 0.f;
    f32x4 o[4] = {};

    *reinterpret_cast<f16x8*>(kb + SWZ(srow, scolB)) =
        *reinterpret_cast<const f16x8*>(Kg + (long)srow * Dc + scolB / 2);
    *reinterpret_cast<f16x8*>(vb + SWZ(srow, scolB)) =
        *reinterpret_cast<const f16x8*>(Vg + (long)srow * Sc + scolB / 2);
    __syncthreads();

    for (int kv0 = 0; kv0 < Sc; kv0 += 64) {
      const bool pf = (kv0 + 64) < Sc;
      f16x8 kr, vr;
      if (pf) {  // T14: issue next-tile loads early; ds_write after barrier
        kr = *reinterpret_cast<const f16x8*>(Kg + (long)(kv0 + 64 + srow) * Dc + scolB / 2);
        vr = *reinterpret_cast<const f16x8*>(Vg + (long)srow * Sc + kv0 + 64 + scolB / 2);
      }

      f32x4 sc[4];
      __builtin_amdgcn_s_setprio(1);
#pragma unroll
      for (int t = 0; t < 4; ++t) {
        const int row = t * 16 + l15;
        f32x4 s = {};
        s = mfma16(*reinterpret_cast<const f16x8*>(kb + SWZ(row, lg * 16)), qf[0], s);
        s = mfma16(*reinterpret_cast<const f16x8*>(kb + SWZ(row, 64 + lg * 16)), qf[1], s);
        sc[t] = s;
      }
      __builtin_amdgcn_s_setprio(0);

      float mx = sc[0][0];
#pragma unroll
      for (int t = 0; t < 4; ++t)
#pragma unroll
        for (int j = 0; j < 4; ++j) mx = fmaxf(mx, sc[t][j]);
      const float mx2 = mx * c2;
      float al = 1.0f;
      if (!__all(mx2 <= m2 + 11.544f)) {
        float gm = fmaxf(mx2, __shfl_xor(mx2, 16));
        gm = fmaxf(gm, __shfl_xor(gm, 32));
        const float mn2 = fmaxf(m2, gm);
        al = __builtin_amdgcn_exp2f(m2 - mn2);
        m2 = mn2;
#pragma unroll
        for (int c = 0; c < 4; ++c)
#pragma unroll
          for (int j = 0; j < 4; ++j) o[c][j] *= al;
      }
      float ps = 0.f;
      f16x4 pp[4];
#pragma unroll
      for (int t = 0; t < 4; ++t)
#pragma unroll
        for (int j = 0; j < 4; ++j) {
          float p = __builtin_amdgcn_exp2f(__builtin_fmaf(sc[t][j], c2, -m2));
          pp[t][j] = (f16)p;
          ps += p;
        }
      ps += __shfl_xor(ps, 16);
      ps += __shfl_xor(ps, 32);
      l_run = l_run * al + ps;

#pragma unroll
      for (int t = 0; t < 4; ++t)
        *reinterpret_cast<f16x4*>(pb + SWZ(l15, t * 32 + lg * 8)) = pp[t];
      asm volatile("s_waitcnt lgkmcnt(0)" ::: "memory");
      __builtin_amdgcn_sched_barrier(0);

      f16x8 pa0 = *reinterpret_cast<const f16x8*>(pb + SWZ(l15, lg * 16));
      f16x8 pa1 = *reinterpret_cast<const f16x8*>(pb + SWZ(l15, 64 + lg * 16));
      __builtin_amdgcn_s_setprio(1);
#pragma unroll
      for (int c = 0; c < 4; ++c) {
        const int row = c * 16 + l15;
        o[c] = mfma16(*reinterpret_cast<const f16x8*>(vb + SWZ(row, lg * 16)), pa0, o[c]);
        o[c] = mfma16(*reinterpret_cast<const f16x8*>(vb + SWZ(row, 64 + lg * 16)), pa1, o[c]);
      }
      __builtin_amdgcn_s_setprio(0);

      if (pf) {
        __syncthreads();
        *reinterpret_cast<f16x8*>(kb + SWZ(srow, scolB)) = kr;
        *reinterpret_cast<f16x8*>(vb + SWZ(srow, scolB)) = vr;
        __syncthreads();
      }
    }

    const float inv = 1.0f / l_run;
    f16* cp = ctx + ((long)(b * Sc) + q0 + l15) * Dc + h * DKc;
#pragma unroll
    for (int c = 0; c < 4; ++c) {
      f16x4 ov;
#pragma unroll
      for (int j = 0; j < 4; ++j) ov[j] = (f16)(o[c][j] * inv);
      *reinterpret_cast<f16x4*>(cp + c * 16 + lg * 4) = ov;
    }
  } else {
    // ======================= avg_weights role =======================
    // chunk -> (batch, 128x128 tile); per-XCD contiguous half-batch chunk.
    const int chunk = xcd * 128 + g * 4 + (r - 3);  // [0,1024)
    const int b  = chunk >> 8;
    const int t  = chunk & 255;
    const long m0 = (long)(t >> 4) * 128;
    const long n0 = (long)(t & 15) * 128;
    const int wr = w >> 2, wc = w & 3;   // 2 x 4 waves, wave tile 64x32

    f16* As = smem;                      // [128][32]
    f16* Bs = smem + 4096;               // [128][32]
    const f16* Ab = Q + (long)b * Sc * Dc + m0 * Dc;
    const f16* Bb = Km + (long)b * Sc * Dc + n0 * Dc;
    const f16* Ag = Ab + (long)(tid >> 2) * Dc + (tid & 3) * 8;
    const f16* Bg = Bb + (long)(tid >> 2) * Dc + (tid & 3) * 8;
    f16* AsD = As + w * 512;             // wave-uniform dest (lane*16B added by HW)
    f16* BsD = Bs + w * 512;

    f32x4 acc[4][2] = {};

    for (int k0 = 0; k0 < Dc; k0 += 32) {
      GLD16(Ag + k0, AsD);
      GLD16(Bg + k0, BsD);
      __syncthreads();
      f16x8 af[4], bf[2];
#pragma unroll
      for (int i = 0; i < 4; ++i)
        af[i] = *reinterpret_cast<const f16x8*>(&As[(wr * 64 + i * 16 + l15) * 32 + lg * 8]);
#pragma unroll
      for (int n = 0; n < 2; ++n)
        bf[n] = *reinterpret_cast<const f16x8*>(&Bs[(wc * 32 + n * 16 + l15) * 32 + lg * 8]);
#pragma unroll
      for (int mi = 0; mi < 4; ++mi)
#pragma unroll
        for (int ni = 0; ni < 2; ++ni)
          acc[mi][ni] = mfma16(af[mi], bf[ni], acc[mi][ni]);
      __syncthreads();
    }

    float* dp = avg + (long)b * Sc * Sc;
#pragma unroll
    for (int mi = 0; mi < 4; ++mi) {
#pragma unroll
      for (int ni = 0; ni < 2; ++ni) {
        const long col = n0 + wc * 32 + ni * 16 + l15;
#pragma unroll
        for (int j = 0; j < 4; ++j) {
          const long row = m0 + wr * 64 + mi * 16 + lg * 4 + j;
          dp[row * Sc + col] = acc[mi][ni][j] * (1.0f / 96.0f);
        }
      }
    }
  }
}

extern "C" void kernel_launch(void* const* d_in, const int* in_sizes, int n_in,
                              void* d_out, int out_size, void* d_ws, size_t ws_size,
                              hipStream_t stream) {
  (void)in_sizes; (void)n_in; (void)out_size; (void)ws_size;
  const float* z    = (const float*)d_in[0];
  const float* wq_w = (const float*)d_in[1];
  const float* wq_b = (const float*)d_in[2];
  const float* wk_w = (const float*)d_in[3];
  const float* wk_b = (const float*)d_in[4];
  const float* wv_w = (const float*)d_in[5];
  const float* wv_b = (const float*)d_in[6];
  const float* fc_w = (const float*)d_in[7];
  const float* fc_b = (const float*)d_in[8];
  float* out = (float*)d_out;

  char* ws = (char*)d_ws;
  size_t off = 0;
  auto alloc = [&](size_t bytes) -> void* {
    void* p = (void*)(ws + off);
    off += (bytes + 255) & ~(size_t)255;
    return p;
  };
  const size_t zdb = (size_t)Bc * Sc * Dc * sizeof(f16);   // 12.6 MB
  const size_t wdb = (size_t)Dc * Dc * sizeof(f16);        // 1.2 MB
  f16* zb  = (f16*)alloc(zdb);
  f16* wqb = (f16*)alloc(wdb);
  f16* wkb = (f16*)alloc(wdb);
  f16* wvb = (f16*)alloc(wdb);
  f16* fcb = (f16*)alloc(wdb);
  f16* Qb  = (f16*)alloc(zdb);
  f16* Kb  = (f16*)alloc(zdb);
  f16* Vt  = (f16*)alloc(zdb);
  f16* Cx  = zb;  // alias: zb is dead after the QKV projection

  cvt5<<<8448, 256, 0, stream>>>(z, wq_w, wk_w, wv_w, fc_w, zb, wqb, wkb, wvb, fcb);

  dim3 gqkv(Bc * Sc / 128, 18, 1);  // 64 x 18 = 1152 blocks
  gemm_qkv<<<gqkv, 256, 0, stream>>>(zb, wqb, wkb, wvb, wq_b, wk_b, wv_b, Qb, Kb, Vt);

  // fused: 768 attn blocks + 1024 avg blocks, role-interleaved 3:4 per XCD
  fused_aw<<<1792, 512, 0, stream>>>(Qb, Kb, Vt, Cx, out + (size_t)Bc * Sc * Dc);

  dim3 gfc(Bc * Sc / 128, Dc / 128, 1);  // 64 x 6
  gemm_fc<<<gfc, 256, 0, stream>>>(Cx, fcb, fc_b, out, Dc, Dc);
}

// Round 6
// 204.875 us; speedup vs baseline: 1.1106x; 1.1106x over previous
//
#include <hip/hip_runtime.h>
#include <hip/hip_fp16.h>

#define Bc 4
#define Sc 2048
#define Dc 768
#define Hc 12
#define DKc 64

typedef _Float16 f16;
typedef __attribute__((ext_vector_type(8))) _Float16 f16x8;
typedef __attribute__((ext_vector_type(4))) _Float16 f16x4;
typedef __attribute__((ext_vector_type(4))) float f32x4;

static __device__ __forceinline__ f32x4 mfma16(f16x8 a, f16x8 b, f32x4 c) {
  return __builtin_amdgcn_mfma_f32_16x16x32_f16(a, b, c, 0, 0, 0);
}

// async global->LDS, 16B per lane. LDS dest is wave-uniform base + lane*16.
#define GLD16(g, l)                                              \
  __builtin_amdgcn_global_load_lds(                              \
      (const __attribute__((address_space(1))) void*)(g),        \
      (__attribute__((address_space(3))) void*)(l), 16, 0, 0)

// T2 XOR swizzle for the attention LDS: row stride 128B.
#define SWZ(row, colB) (((row) << 7) + ((colB) ^ (((row) & 7) << 4)))

// ---------------- fused f32 -> f16 conversion (5 segments) ----------------
__global__ __launch_bounds__(256) void cvt5(
    const float* __restrict__ z, const float* __restrict__ w0,
    const float* __restrict__ w1, const float* __restrict__ w2,
    const float* __restrict__ w3, f16* __restrict__ oz, f16* __restrict__ o0,
    f16* __restrict__ o1, f16* __restrict__ o2, f16* __restrict__ o3) {
  const int bid = blockIdx.x;
  const float* in;
  f16* out;
  int i0;
  if (bid < 6144)      { in = z;  out = oz; i0 = bid * 256; }
  else if (bid < 6720) { in = w0; out = o0; i0 = (bid - 6144) * 256; }
  else if (bid < 7296) { in = w1; out = o1; i0 = (bid - 6720) * 256; }
  else if (bid < 7872) { in = w2; out = o2; i0 = (bid - 7296) * 256; }
  else                 { in = w3; out = o3; i0 = (bid - 7872) * 256; }
  const int i = i0 + threadIdx.x;
  float4 v = reinterpret_cast<const float4*>(in)[i];
  f16x4 o;
  o[0] = (f16)v.x; o[1] = (f16)v.y; o[2] = (f16)v.z; o[3] = (f16)v.w;
  reinterpret_cast<f16x4*>(out)[i] = o;
}

// ========== 256x256 BK=32 depth-2 counted-vmcnt pipelined GEMM ==============
// 8 waves (2M x 4N), per-wave 128x64 out, acc[8][4]. Raw s_barrier; vmcnt
// never drained to 0 in the main loop (T4). K = 768 (24 K-steps) hardcoded.
// MODE 0: fused QKV projection. A = zb [8192 x 768]; per-block n-tile selects
//         {wq,wk,wv}; Q/K stored f16 row-major, V stored transposed [B,D,S].
// MODE 1: avg_weights. A = Q[b], B = K[b], dst f32 [b][2048][2048] * 1/96.
template <int MODE>
__global__ __launch_bounds__(512, 2) void gemm256x(
    const f16* __restrict__ A0, const f16* __restrict__ W0,
    const f16* __restrict__ W1, const f16* __restrict__ W2,
    const float* __restrict__ bq, const float* __restrict__ bk,
    const float* __restrict__ bv, f16* __restrict__ Qb, f16* __restrict__ Kb,
    f16* __restrict__ Vt, float* __restrict__ avg) {
  constexpr int K = Dc;           // 768
  constexpr int NK = K / 32;      // 24 K-steps
  const int tid = threadIdx.x;
  const int lane = tid & 63;
  const int w = tid >> 6;         // 0..7
  const int wr = w >> 2, wc = w & 3;
  const int l15 = lane & 15, lg = lane >> 4;

  // block -> tile mapping (XCD-chunked for L2 locality)
  const f16* Ab;
  const f16* Bb;
  long m0;
  int seg = 0, n0seg = 0, bat = 0, ncol0 = 0;
  if (MODE == 0) {
    const int wgid = (blockIdx.x & 7) * 36 + (blockIdx.x >> 3);  // 288 = 8*36
    const int mx = wgid / 9, nt = wgid % 9;
    m0 = (long)mx * 256;
    seg = nt / 3;
    n0seg = (nt % 3) * 256;
    const f16* Wsel = seg == 0 ? W0 : seg == 1 ? W1 : W2;
    Ab = A0 + m0 * K;
    Bb = Wsel + (long)n0seg * K;
  } else {
    const int wgid = (blockIdx.x & 7) * 32 + (blockIdx.x >> 3);  // 256 = 8*32
    bat = wgid >> 6;
    const int t = wgid & 63;
    const int mx = t >> 3, nx = t & 7;
    m0 = (long)mx * 256;
    ncol0 = nx * 256;
    Ab = W0 + (long)bat * Sc * Dc + m0 * K;      // Q[b]
    Bb = W1 + (long)bat * Sc * Dc + (long)ncol0 * K;  // K[b]
  }

  __shared__ f16 AB[2][2][256 * 32];  // [buf][A/B][rows*cols] = 64 KB

  // staging addresses: gload g covers tile rows [(w*2+g)*16, +16)
  const int strow = (w * 2) * 16 + (lane >> 2);
  const int stcol = (lane & 3) * 8;
  const f16* Ag0 = Ab + (long)strow * K + stcol;
  const f16* Ag1 = Ag0 + (long)16 * K;
  const f16* Bg0 = Bb + (long)strow * K + stcol;
  const f16* Bg1 = Bg0 + (long)16 * K;
  const int so0 = w * 1024;        // f16 offset of wave's region (+lane*16B HW)
  const int so1 = w * 1024 + 512;

#define STG(buf, k0)                          \
  {                                           \
    GLD16(Ag0 + (k0), &AB[buf][0][so0]);      \
    GLD16(Ag1 + (k0), &AB[buf][0][so1]);      \
    GLD16(Bg0 + (k0), &AB[buf][1][so0]);      \
    GLD16(Bg1 + (k0), &AB[buf][1][so1]);      \
  }

  f32x4 acc[8][4] = {};

  STG(0, 0)
  STG(1, 32)

#pragma unroll 1
  for (int i = 0; i < NK; ++i) {
    if (i + 1 < NK) {
      asm volatile("s_waitcnt vmcnt(4)" ::: "memory");
    } else {
      asm volatile("s_waitcnt vmcnt(0)" ::: "memory");
    }
    __builtin_amdgcn_sched_barrier(0);
    __builtin_amdgcn_s_barrier();
    __builtin_amdgcn_sched_barrier(0);

    const f16* Asb = &AB[i & 1][0][0];
    const f16* Bsb = &AB[i & 1][1][0];
    f16x8 af[8], bf[4];
#pragma unroll
    for (int mi = 0; mi < 8; ++mi)
      af[mi] = *reinterpret_cast<const f16x8*>(
          &Asb[(wr * 128 + mi * 16 + l15) * 32 + lg * 8]);
#pragma unroll
    for (int ni = 0; ni < 4; ++ni)
      bf[ni] = *reinterpret_cast<const f16x8*>(
          &Bsb[(wc * 64 + ni * 16 + l15) * 32 + lg * 8]);
#pragma unroll
    for (int mi = 0; mi < 8; ++mi)
#pragma unroll
      for (int ni = 0; ni < 4; ++ni)
        acc[mi][ni] = mfma16(af[mi], bf[ni], acc[mi][ni]);

    __builtin_amdgcn_sched_barrier(0);
    __builtin_amdgcn_s_barrier();
    __builtin_amdgcn_sched_barrier(0);
    if (i + 2 < NK) STG(i & 1, (i + 2) * 32)
  }
#undef STG

  // ---------------- epilogue ----------------
  if (MODE == 0) {
    const float* bias = seg == 0 ? bq : seg == 1 ? bk : bv;
    float bvv[4];
#pragma unroll
    for (int ni = 0; ni < 4; ++ni)
      bvv[ni] = bias[n0seg + wc * 64 + ni * 16 + l15];
    if (seg < 2) {
      f16* dq = seg == 0 ? Qb : Kb;
#pragma unroll
      for (int mi = 0; mi < 8; ++mi) {
#pragma unroll
        for (int ni = 0; ni < 4; ++ni) {
          const long col = n0seg + wc * 64 + ni * 16 + l15;
#pragma unroll
          for (int j = 0; j < 4; ++j) {
            const long row = m0 + wr * 128 + mi * 16 + lg * 4 + j;
            dq[row * Dc + col] = (f16)(acc[mi][ni][j] + bvv[ni]);
          }
        }
      }
    } else {
#pragma unroll
      for (int mi = 0; mi < 8; ++mi) {
#pragma unroll
        for (int ni = 0; ni < 4; ++ni) {
          const long col = n0seg + wc * 64 + ni * 16 + l15;
#pragma unroll
          for (int j = 0; j < 4; ++j) {
            const long row = m0 + wr * 128 + mi * 16 + lg * 4 + j;
            const long b = row >> 11, s = row & 2047;
            Vt[(b * Dc + col) * (long)Sc + s] = (f16)(acc[mi][ni][j] + bvv[ni]);
          }
        }
      }
    }
  } else {
    float* dp = avg + (long)bat * Sc * Sc;
#pragma unroll
    for (int mi = 0; mi < 8; ++mi) {
#pragma unroll
      for (int ni = 0; ni < 4; ++ni) {
        const long col = ncol0 + wc * 64 + ni * 16 + l15;
#pragma unroll
        for (int j = 0; j < 4; ++j) {
          const long row = m0 + wr * 128 + mi * 16 + lg * 4 + j;
          dp[row * Sc + col] = acc[mi][ni][j] * (1.0f / 96.0f);
        }
      }
    }
  }
}

// ------------- 128x128 MFMA GEMM body, 4 waves (m97 structure) --------------
#define GEMM_CORE(Ab, Bb, K)                                                   \
  __shared__ f16 As[128][32];                                                  \
  __shared__ f16 Bs[128][32];                                                  \
  f32x4 acc[4][4] = {};                                                        \
  const int srow = lane >> 2;                                                  \
  const int scol = (lane & 3) * 8;                                             \
  const f16* Ag = (Ab) + (long)(w * 32 + srow) * (K) + scol;                   \
  const f16* Bg = (Bb) + (long)(w * 32 + srow) * (K) + scol;                   \
  f16* As0 = &As[w * 32][0];                                                   \
  f16* As1 = &As[w * 32 + 16][0];                                              \
  f16* Bs0 = &Bs[w * 32][0];                                                   \
  f16* Bs1 = &Bs[w * 32 + 16][0];                                              \
  const long k16 = (long)16 * (K);                                             \
  for (int k0 = 0; k0 < (K); k0 += 32) {                                       \
    GLD16(Ag + k0, As0);                                                       \
    GLD16(Ag + k0 + k16, As1);                                                 \
    GLD16(Bg + k0, Bs0);                                                       \
    GLD16(Bg + k0 + k16, Bs1);                                                 \
    __syncthreads();                                                           \
    f16x8 af[4], bf[4];                                                        \
    _Pragma("unroll") for (int i = 0; i < 4; ++i) {                            \
      af[i] = *reinterpret_cast<const f16x8*>(&As[wr * 64 + i * 16 + l15][lg * 8]); \
      bf[i] = *reinterpret_cast<const f16x8*>(&Bs[wc * 64 + i * 16 + l15][lg * 8]); \
    }                                                                          \
    _Pragma("unroll") for (int mi = 0; mi < 4; ++mi)                           \
      _Pragma("unroll") for (int ni = 0; ni < 4; ++ni)                         \
        acc[mi][ni] = mfma16(af[mi], bf[ni], acc[mi][ni]);                     \
    __syncthreads();                                                           \
  }

// fc: dst f32 row-major [M][N], + bias.
__global__ __launch_bounds__(256) void gemm_fc(
    const f16* __restrict__ A, const f16* __restrict__ Bw,
    const float* __restrict__ bias, float* __restrict__ dst, int N, int K) {
  const int tid = threadIdx.x;
  const int lane = tid & 63;
  const int w = tid >> 6;
  const int wr = w >> 1, wc = w & 1;
  const int l15 = lane & 15, lg = lane >> 4;
  const long m0 = (long)blockIdx.x * 128;
  const long n0 = (long)blockIdx.y * 128;
  const f16* Ab = A + m0 * K;
  const f16* Bb = Bw + n0 * K;

  GEMM_CORE(Ab, Bb, K)

#pragma unroll
  for (int mi = 0; mi < 4; ++mi) {
#pragma unroll
    for (int ni = 0; ni < 4; ++ni) {
      const long col = n0 + wc * 64 + ni * 16 + l15;
      const float bv = bias[col];
#pragma unroll
      for (int j = 0; j < 4; ++j) {
        const long row = m0 + wr * 64 + mi * 16 + lg * 4 + j;
        dst[row * N + col] = acc[mi][ni][j] + bv;
      }
    }
  }
}

// -------- flash attention: 8 waves/block, 128 q-rows, KVBLK=64 --------------
// (R4-verified kernel, unchanged: 82.7 us)
__global__ __launch_bounds__(512) void attn8(const f16* __restrict__ Q,
                                             const f16* __restrict__ Km,
                                             const f16* __restrict__ Vt,
                                             f16* __restrict__ ctx) {
  const int tid = threadIdx.x;
  const int lane = tid & 63;
  const int w = tid >> 6;              // 0..7
  const int l15 = lane & 15, lg = lane >> 4;
  const int lid = (blockIdx.x & 7) * 96 + (blockIdx.x >> 3);
  const int qt = lid & 15;
  const int h  = (lid >> 4) % Hc;
  const int b  = lid / (16 * Hc);
  const int q0 = qt * 128 + w * 16;

  __shared__ f16 Ks[64 * 64];
  __shared__ f16 Vs[64 * 64];
  __shared__ f16 Ps[8 * 16 * 64];
  char* kb = (char*)Ks;
  char* vb = (char*)Vs;
  char* pb = (char*)Ps + (w << 11);    // per-wave 2KB

  f16x8 qf[2];
  {
    const f16* qp = Q + ((long)(b * Sc + q0 + l15)) * Dc + h * DKc + lg * 8;
    qf[0] = *reinterpret_cast<const f16x8*>(qp);
    qf[1] = *reinterpret_cast<const f16x8*>(qp + 32);
  }

  const int srow = tid >> 3;           // 0..63
  const int scolB = (tid & 7) * 16;    // byte col 0..112
  const f16* Kg = Km + (long)(b * Sc) * Dc + h * DKc;
  const f16* Vg = Vt + ((long)(b * Dc + h * DKc)) * Sc;

  const float c2 = 0.18033688011f;     // log2(e) / temp, temp = 8
  float m2 = -1e30f, l_run = 0.f;
  f32x4 o[4] = {};

  *reinterpret_cast<f16x8*>(kb + SWZ(srow, scolB)) =
      *reinterpret_cast<const f16x8*>(Kg + (long)srow * Dc + scolB / 2);
  *reinterpret_cast<f16x8*>(vb + SWZ(srow, scolB)) =
      *reinterpret_cast<const f16x8*>(Vg + (long)srow * Sc + scolB / 2);
  __syncthreads();

  for (int kv0 = 0; kv0 < Sc; kv0 += 64) {
    const bool pf = (kv0 + 64) < Sc;
    f16x8 kr, vr;
    if (pf) {  // T14: issue next-tile loads early; ds_write after barrier
      kr = *reinterpret_cast<const f16x8*>(Kg + (long)(kv0 + 64 + srow) * Dc + scolB / 2);
      vr = *reinterpret_cast<const f16x8*>(Vg + (long)srow * Sc + kv0 + 64 + scolB / 2);
    }

    f32x4 sc[4];
    __builtin_amdgcn_s_setprio(1);
#pragma unroll
    for (int t = 0; t < 4; ++t) {
      const int row = t * 16 + l15;
      f32x4 s = {};
      s = mfma16(*reinterpret_cast<const f16x8*>(kb + SWZ(row, lg * 16)), qf[0], s);
      s = mfma16(*reinterpret_cast<const f16x8*>(kb + SWZ(row, 64 + lg * 16)), qf[1], s);
      sc[t] = s;
    }
    __builtin_amdgcn_s_setprio(0);

    float mx = sc[0][0];
#pragma unroll
    for (int t = 0; t < 4; ++t)
#pragma unroll
      for (int j = 0; j < 4; ++j) mx = fmaxf(mx, sc[t][j]);
    const float mx2 = mx * c2;
    float al = 1.0f;
    if (!__all(mx2 <= m2 + 11.544f)) {
      float g = fmaxf(mx2, __shfl_xor(mx2, 16));
      g = fmaxf(g, __shfl_xor(g, 32));
      const float mn2 = fmaxf(m2, g);
      al = __builtin_amdgcn_exp2f(m2 - mn2);
      m2 = mn2;
#pragma unroll
      for (int c = 0; c < 4; ++c)
#pragma unroll
        for (int j = 0; j < 4; ++j) o[c][j] *= al;
    }
    float ps = 0.f;
    f16x4 pp[4];
#pragma unroll
    for (int t = 0; t < 4; ++t)
#pragma unroll
      for (int j = 0; j < 4; ++j) {
        float p = __builtin_amdgcn_exp2f(__builtin_fmaf(sc[t][j], c2, -m2));
        pp[t][j] = (f16)p;
        ps += p;
      }
    ps += __shfl_xor(ps, 16);
    ps += __shfl_xor(ps, 32);
    l_run = l_run * al + ps;

#pragma unroll
    for (int t = 0; t < 4; ++t)
      *reinterpret_cast<f16x4*>(pb + SWZ(l15, t * 32 + lg * 8)) = pp[t];
    asm volatile("s_waitcnt lgkmcnt(0)" ::: "memory");
    __builtin_amdgcn_sched_barrier(0);

    f16x8 pa0 = *reinterpret_cast<const f16x8*>(pb + SWZ(l15, lg * 16));
    f16x8 pa1 = *reinterpret_cast<const f16x8*>(pb + SWZ(l15, 64 + lg * 16));
    __builtin_amdgcn_s_setprio(1);
#pragma unroll
    for (int c = 0; c < 4; ++c) {
      const int row = c * 16 + l15;
      o[c] = mfma16(*reinterpret_cast<const f16x8*>(vb + SWZ(row, lg * 16)), pa0, o[c]);
      o[c] = mfma16(*reinterpret_cast<const f16x8*>(vb + SWZ(row, 64 + lg * 16)), pa1, o[c]);
    }
    __builtin_amdgcn_s_setprio(0);

    if (pf) {
      __syncthreads();
      *reinterpret_cast<f16x8*>(kb + SWZ(srow, scolB)) = kr;
      *reinterpret_cast<f16x8*>(vb + SWZ(srow, scolB)) = vr;
      __syncthreads();
    }
  }

  const float inv = 1.0f / l_run;
  f16* cp = ctx + ((long)(b * Sc) + q0 + l15) * Dc + h * DKc;
#pragma unroll
  for (int c = 0; c < 4; ++c) {
    f16x4 ov;
#pragma unroll
    for (int j = 0; j < 4; ++j) ov[j] = (f16)(o[c][j] * inv);
    *reinterpret_cast<f16x4*>(cp + c * 16 + lg * 4) = ov;
  }
}

extern "C" void kernel_launch(void* const* d_in, const int* in_sizes, int n_in,
                              void* d_out, int out_size, void* d_ws, size_t ws_size,
                              hipStream_t stream) {
  (void)in_sizes; (void)n_in; (void)out_size; (void)ws_size;
  const float* z    = (const float*)d_in[0];
  const float* wq_w = (const float*)d_in[1];
  const float* wq_b = (const float*)d_in[2];
  const float* wk_w = (const float*)d_in[3];
  const float* wk_b = (const float*)d_in[4];
  const float* wv_w = (const float*)d_in[5];
  const float* wv_b = (const float*)d_in[6];
  const float* fc_w = (const float*)d_in[7];
  const float* fc_b = (const float*)d_in[8];
  float* out = (float*)d_out;

  char* ws = (char*)d_ws;
  size_t off = 0;
  auto alloc = [&](size_t bytes) -> void* {
    void* p = (void*)(ws + off);
    off += (bytes + 255) & ~(size_t)255;
    return p;
  };
  const size_t zdb = (size_t)Bc * Sc * Dc * sizeof(f16);   // 12.6 MB
  const size_t wdb = (size_t)Dc * Dc * sizeof(f16);        // 1.2 MB
  f16* zb  = (f16*)alloc(zdb);
  f16* wqb = (f16*)alloc(wdb);
  f16* wkb = (f16*)alloc(wdb);
  f16* wvb = (f16*)alloc(wdb);
  f16* fcb = (f16*)alloc(wdb);
  f16* Qb  = (f16*)alloc(zdb);
  f16* Kb  = (f16*)alloc(zdb);
  f16* Vt  = (f16*)alloc(zdb);
  f16* Cx  = zb;  // alias: zb is dead after the QKV projection

  cvt5<<<8448, 256, 0, stream>>>(z, wq_w, wk_w, wv_w, fc_w, zb, wqb, wkb, wvb, fcb);

  // fused QKV projection: 288 blocks (256^2 tiles, deep pipeline)
  gemm256x<0><<<288, 512, 0, stream>>>(zb, wqb, wkb, wvb, wq_b, wk_b, wv_b,
                                       Qb, Kb, Vt, nullptr);

  // avg_weights = (Qfull @ Kfull^T) / 96: 256 blocks
  gemm256x<1><<<256, 512, 0, stream>>>(nullptr, Qb, Kb, nullptr, nullptr,
                                       nullptr, nullptr, nullptr, nullptr,
                                       nullptr, out + (size_t)Bc * Sc * Dc);

  attn8<<<Bc * Hc * (Sc / 128), 512, 0, stream>>>(Qb, Kb, Vt, Cx);

  dim3 gfc(Bc * Sc / 128, Dc / 128, 1);  // 64 x 6
  gemm_fc<<<gfc, 256, 0, stream>>>(Cx, fcb, fc_b, out, Dc, Dc);
}